// Round 1
// baseline (367.802 us; speedup 1.0000x reference)
//
#include <hip/hip_runtime.h>
#include <math.h>

#define B_ROWS 8192
#define D_DIM 64
#define C_DIM 16
#define NBLK1 64
#define ROWS_PER_BLK 128   // 8192 / NBLK1
#define CHUNK 8

// ws layout (floats):
//   pH   : NBLK1 * 4096   = 262144
//   pA   : NBLK1 * 1024   =  65536
//   pR   : NBLK1 * 1024   =  65536
//   invn : 8192
//   W    : 1024
#define WS_PH   0
#define WS_PA   262144
#define WS_PR   327680
#define WS_INVN 393216
#define WS_W    401408

__global__ __launch_bounds__(256) void lp_k1(const float* __restrict__ F,
        const int* __restrict__ lab, const int* __restrict__ mask,
        float* __restrict__ pH, float* __restrict__ pA, float* __restrict__ pR,
        float* __restrict__ invn)
{
    __shared__ float cJ[ROWS_PER_BLK];      // mask_j * (1/||f_j||)
    __shared__ float fbuf[CHUNK][D_DIM];
    __shared__ float labf[CHUNK][C_DIM];
    __shared__ float mflag[CHUNK];
    const int t = threadIdx.x;
    const int row0 = blockIdx.x * ROWS_PER_BLK;

    // phase 1: row norms (threads 0..127, one row each)
    if (t < ROWS_PER_BLK) {
        const float4* fr = (const float4*)(F + (size_t)(row0 + t) * D_DIM);
        float ss = 0.0f;
        #pragma unroll
        for (int q = 0; q < 16; ++q) {
            float4 v = fr[q];
            ss += v.x*v.x + v.y*v.y + v.z*v.z + v.w*v.w;
        }
        float iv = 1.0f / sqrtf(ss);
        invn[row0 + t] = iv;
        cJ[t] = mask[row0 + t] ? iv : 0.0f;
    }
    __syncthreads();

    // phase 2: accumulate partial H (64x64), A (64x16), r0 (64x16)
    float h[16];
    float aacc[4], racc[4];
    #pragma unroll
    for (int k = 0; k < 16; ++k) h[k] = 0.0f;
    #pragma unroll
    for (int j = 0; j < 4; ++j) { aacc[j] = 0.0f; racc[j] = 0.0f; }

    const int d1  = t >> 2;          // H row owned by this thread
    const int d2b = (t & 3) << 4;    // H col block base (16 cols)

    for (int ch = 0; ch < ROWS_PER_BLK / CHUNK; ++ch) {
        for (int e = t; e < CHUNK * D_DIM; e += 256) {
            int r = e >> 6, d = e & 63;
            fbuf[r][d] = F[(size_t)(row0 + ch*CHUNK + r) * D_DIM + d];
        }
        if (t < CHUNK * C_DIM) {
            int r = t >> 4, c = t & 15;
            labf[r][c] = (float)lab[(size_t)(row0 + ch*CHUNK + r) * C_DIM + c];
        }
        if (t < CHUNK) mflag[t] = mask[row0 + ch*CHUNK + t] ? 1.0f : 0.0f;
        __syncthreads();

        #pragma unroll
        for (int r = 0; r < CHUNK; ++r) {
            float coef = cJ[ch*CHUNK + r];
            float fd1 = fbuf[r][d1] * coef;
            #pragma unroll
            for (int k = 0; k < 16; ++k)
                h[k] += fd1 * fbuf[r][d2b + k];
            float mf  = mflag[r];
            float nmf = 1.0f - mf;
            #pragma unroll
            for (int j = 0; j < 4; ++j) {
                int e = t*4 + j;
                int dd = e >> 4, cc = e & 15;
                float fl = fbuf[r][dd] * labf[r][cc];
                aacc[j] += nmf * fl;
                racc[j] += mf  * fl;
            }
        }
        __syncthreads();
    }

    #pragma unroll
    for (int k = 0; k < 16; ++k)
        pH[(size_t)blockIdx.x * 4096 + t*16 + k] = h[k];
    #pragma unroll
    for (int j = 0; j < 4; ++j) {
        pA[(size_t)blockIdx.x * 1024 + t*4 + j] = aacc[j];
        pR[(size_t)blockIdx.x * 1024 + t*4 + j] = racc[j];
    }
}

__global__ __launch_bounds__(1024) void lp_k2(const float* __restrict__ pH,
        const float* __restrict__ pA, const float* __restrict__ pR,
        float* __restrict__ Wout)
{
    __shared__ float Hs[4096];
    __shared__ float As[1024];
    __shared__ float Rs[1024];
    __shared__ float Gs[1024];
    const int t = threadIdx.x;

    // deterministic reduction of per-block partials (fixed order over b)
    #pragma unroll
    for (int j = 0; j < 4; ++j) {
        int e = t*4 + j;
        float s = 0.0f;
        for (int b = 0; b < NBLK1; ++b) s += pH[(size_t)b*4096 + e];
        Hs[e] = s;
    }
    {
        float sa = 0.0f, sr = 0.0f;
        for (int b = 0; b < NBLK1; ++b) {
            sa += pA[(size_t)b*1024 + t];
            sr += pR[(size_t)b*1024 + t];
        }
        As[t] = sa;
        Rs[t] = sr;
    }
    __syncthreads();

    const int d = t >> 4, c = t & 15;
    float w = 0.0f;
    for (int it = 0; it < 100; ++it) {
        float g = Rs[t] + (it > 0 ? As[t] : 0.0f);   // G_t = r_t + A (t>=1)
        Gs[t] = g;
        w = 0.9f*w + 0.1f*g;                          // W accumulation
        __syncthreads();
        float hg = 0.0f;
        #pragma unroll
        for (int k = 0; k < 64; ++k)
            hg += Hs[d*64 + k] * Gs[k*16 + c];
        Rs[t] = 0.9f*Rs[t] + 0.1f*hg;                 // r_{t+1}
        __syncthreads();
    }
    Wout[t] = w;
}

__global__ __launch_bounds__(256) void lp_k3(const float* __restrict__ F,
        const int* __restrict__ lab, const int* __restrict__ mask,
        const float* __restrict__ invn, const float* __restrict__ Win,
        float* __restrict__ out)
{
    __shared__ float Ws[64][16];
    const int t = threadIdx.x;
    #pragma unroll
    for (int j = 0; j < 4; ++j)
        ((float*)Ws)[t*4 + j] = Win[t*4 + j];
    __syncthreads();

    const int row = blockIdx.x * 256 + t;
    const float4* fr = (const float4*)(F + (size_t)row * D_DIM);
    float acc[16];
    #pragma unroll
    for (int c = 0; c < 16; ++c) acc[c] = 0.0f;
    #pragma unroll
    for (int q = 0; q < 16; ++q) {
        float4 v = fr[q];
        int d = q * 4;
        #pragma unroll
        for (int c = 0; c < 16; ++c)
            acc[c] += v.x*Ws[d][c] + v.y*Ws[d+1][c] + v.z*Ws[d+2][c] + v.w*Ws[d+3][c];
    }

    const float iv  = invn[row];
    const float mf  = (float)mask[row];
    const float nmf = 1.0f - mf;
    const float P100 = 2.6561398887587544e-5f;  // 0.9^100

    float p[16];
    #pragma unroll
    for (int c = 0; c < 16; ++c) {
        float lf  = (float)lab[(size_t)row * C_DIM + c];
        float upd = P100 * (lf * mf) + acc[c] * iv;   // 0.9^100 * p0 + D^-1 F W
        p[c] = upd * mf + lf * nmf;                   // literal mask arithmetic (NaN-faithful)
    }

    // numpy-compatible argmax: NaN treated as greatest, first occurrence wins
    float best = p[0];
    int idx = 0;
    #pragma unroll
    for (int c = 1; c < 16; ++c) {
        bool take = (p[c] > best) || ((p[c] != p[c]) && !(best != best));
        if (take) { best = p[c]; idx = c; }
    }
    out[row] = (float)idx;
}

extern "C" void kernel_launch(void* const* d_in, const int* in_sizes, int n_in,
                              void* d_out, int out_size, void* d_ws, size_t ws_size,
                              hipStream_t stream) {
    const float* F   = (const float*)d_in[0];
    const int* lab   = (const int*)d_in[1];
    const int* mask  = (const int*)d_in[2];
    float* ws   = (float*)d_ws;
    float* pH   = ws + WS_PH;
    float* pA   = ws + WS_PA;
    float* pR   = ws + WS_PR;
    float* invn = ws + WS_INVN;
    float* W    = ws + WS_W;
    float* out  = (float*)d_out;

    lp_k1<<<NBLK1, 256, 0, stream>>>(F, lab, mask, pH, pA, pR, invn);
    lp_k2<<<1, 1024, 0, stream>>>(pH, pA, pR, W);
    lp_k3<<<32, 256, 0, stream>>>(F, lab, mask, invn, W, out);
}

// Round 2
// 145.635 us; speedup vs baseline: 2.5255x; 2.5255x over previous
//
#include <hip/hip_runtime.h>
#include <math.h>

#define B_ROWS 8192
#define D_DIM 64
#define C_DIM 16
#define NBLK1 64
#define ROWS_PER_BLK 128   // 8192 / NBLK1
#define CHUNK 8

// ws layout (floats):
//   pH    : NBLK1 * 4096   = 262144
//   pA    : NBLK1 * 1024   =  65536
//   pR    : NBLK1 * 1024   =  65536
//   invn  : 8192
//   W     : 1024
//   Hfull : 4096
//   Afull : 1024
//   Rfull : 1024
#define WS_PH    0
#define WS_PA    262144
#define WS_PR    327680
#define WS_INVN  393216
#define WS_W     401408
#define WS_HF    402432
#define WS_AF    406528
#define WS_RF    407552

__global__ __launch_bounds__(256) void lp_k1(const float* __restrict__ F,
        const int* __restrict__ lab, const int* __restrict__ mask,
        float* __restrict__ pH, float* __restrict__ pA, float* __restrict__ pR,
        float* __restrict__ invn)
{
    __shared__ float cJ[ROWS_PER_BLK];      // mask_j * (1/||f_j||)
    __shared__ float fbuf[CHUNK][D_DIM];
    __shared__ float labf[CHUNK][C_DIM];
    __shared__ float mflag[CHUNK];
    const int t = threadIdx.x;
    const int row0 = blockIdx.x * ROWS_PER_BLK;

    // phase 1: row norms (threads 0..127, one row each)
    if (t < ROWS_PER_BLK) {
        const float4* fr = (const float4*)(F + (size_t)(row0 + t) * D_DIM);
        float ss = 0.0f;
        #pragma unroll
        for (int q = 0; q < 16; ++q) {
            float4 v = fr[q];
            ss += v.x*v.x + v.y*v.y + v.z*v.z + v.w*v.w;
        }
        float iv = 1.0f / sqrtf(ss);
        invn[row0 + t] = iv;
        cJ[t] = mask[row0 + t] ? iv : 0.0f;
    }
    __syncthreads();

    // phase 2: accumulate partial H (64x64), A (64x16), r0 (64x16)
    float h[16];
    float aacc[4], racc[4];
    #pragma unroll
    for (int k = 0; k < 16; ++k) h[k] = 0.0f;
    #pragma unroll
    for (int j = 0; j < 4; ++j) { aacc[j] = 0.0f; racc[j] = 0.0f; }

    const int d1  = t >> 2;          // H row owned by this thread
    const int d2b = (t & 3) << 4;    // H col block base (16 cols)

    for (int ch = 0; ch < ROWS_PER_BLK / CHUNK; ++ch) {
        for (int e = t; e < CHUNK * D_DIM; e += 256) {
            int r = e >> 6, d = e & 63;
            fbuf[r][d] = F[(size_t)(row0 + ch*CHUNK + r) * D_DIM + d];
        }
        if (t < CHUNK * C_DIM) {
            int r = t >> 4, c = t & 15;
            labf[r][c] = (float)lab[(size_t)(row0 + ch*CHUNK + r) * C_DIM + c];
        }
        if (t < CHUNK) mflag[t] = mask[row0 + ch*CHUNK + t] ? 1.0f : 0.0f;
        __syncthreads();

        #pragma unroll
        for (int r = 0; r < CHUNK; ++r) {
            float coef = cJ[ch*CHUNK + r];
            float fd1 = fbuf[r][d1] * coef;
            #pragma unroll
            for (int k = 0; k < 16; ++k)
                h[k] += fd1 * fbuf[r][d2b + k];
            float mf  = mflag[r];
            float nmf = 1.0f - mf;
            #pragma unroll
            for (int j = 0; j < 4; ++j) {
                int e = t*4 + j;
                int dd = e >> 4, cc = e & 15;
                float fl = fbuf[r][dd] * labf[r][cc];
                aacc[j] += nmf * fl;
                racc[j] += mf  * fl;
            }
        }
        __syncthreads();
    }

    #pragma unroll
    for (int k = 0; k < 16; ++k)
        pH[(size_t)blockIdx.x * 4096 + t*16 + k] = h[k];
    #pragma unroll
    for (int j = 0; j < 4; ++j) {
        pA[(size_t)blockIdx.x * 1024 + t*4 + j] = aacc[j];
        pR[(size_t)blockIdx.x * 1024 + t*4 + j] = racc[j];
    }
}

// reduce the 64 per-block partials -> Hfull (4096), Afull (1024), Rfull (1024)
__global__ __launch_bounds__(256) void lp_k1b(const float* __restrict__ pH,
        const float* __restrict__ pA, const float* __restrict__ pR,
        float* __restrict__ Hf, float* __restrict__ Af, float* __restrict__ Rf)
{
    const int e = blockIdx.x * 256 + threadIdx.x;   // 0..6143
    if (e < 4096) {
        float s = 0.0f;
        for (int b = 0; b < NBLK1; ++b) s += pH[(size_t)b * 4096 + e];
        Hf[e] = s;
    } else if (e < 5120) {
        const int i = e - 4096;
        float s = 0.0f;
        for (int b = 0; b < NBLK1; ++b) s += pA[(size_t)b * 1024 + i];
        Af[i] = s;
    } else {
        const int i = e - 5120;
        float s = 0.0f;
        for (int b = 0; b < NBLK1; ++b) s += pR[(size_t)b * 1024 + i];
        Rf[i] = s;
    }
}

// 16 independent column evolutions: block c, one wave, lane = d.
// H row in 64 VGPRs; per step only a 64-float LDS broadcast of g.
__global__ __launch_bounds__(64) void lp_k2(const float* __restrict__ Hf,
        const float* __restrict__ Af, const float* __restrict__ Rf,
        float* __restrict__ Wout)
{
    __shared__ __align__(16) float gs[64];
    const int d = threadIdx.x;
    const int c = blockIdx.x;

    float4 hq[16];
    const float4* Hrow = (const float4*)(Hf + d * 64);
    #pragma unroll
    for (int q = 0; q < 16; ++q) hq[q] = Hrow[q];

    float a = Af[d * 16 + c];
    float r = Rf[d * 16 + c];
    float w = 0.0f;

    for (int it = 0; it < 100; ++it) {
        float g = r + (it > 0 ? a : 0.0f);   // G_t = r_t + A (t>=1)
        w = 0.9f * w + 0.1f * g;
        gs[d] = g;
        __syncthreads();
        float acc0 = 0.0f, acc1 = 0.0f, acc2 = 0.0f, acc3 = 0.0f;
        #pragma unroll
        for (int q = 0; q < 16; ++q) {
            const float4 gv = *((const float4*)(gs + q * 4));  // uniform addr -> broadcast
            acc0 += hq[q].x * gv.x;
            acc1 += hq[q].y * gv.y;
            acc2 += hq[q].z * gv.z;
            acc3 += hq[q].w * gv.w;
        }
        r = 0.9f * r + 0.1f * ((acc0 + acc1) + (acc2 + acc3));
        __syncthreads();
    }
    Wout[d * 16 + c] = w;
}

__global__ __launch_bounds__(256) void lp_k3(const float* __restrict__ F,
        const int* __restrict__ lab, const int* __restrict__ mask,
        const float* __restrict__ invn, const float* __restrict__ Win,
        float* __restrict__ out)
{
    __shared__ __align__(16) float Ws[64][16];
    const int t = threadIdx.x;
    #pragma unroll
    for (int j = 0; j < 4; ++j)
        ((float*)Ws)[t*4 + j] = Win[t*4 + j];
    __syncthreads();

    const int row = blockIdx.x * 256 + t;
    const float4* fr = (const float4*)(F + (size_t)row * D_DIM);
    float acc[16];
    #pragma unroll
    for (int c = 0; c < 16; ++c) acc[c] = 0.0f;

    #pragma unroll
    for (int q = 0; q < 16; ++q) {
        float4 v = fr[q];
        #pragma unroll
        for (int dd = 0; dd < 4; ++dd) {
            const float fv = (dd == 0) ? v.x : (dd == 1) ? v.y : (dd == 2) ? v.z : v.w;
            const float4* wr = (const float4*)(&Ws[q*4 + dd][0]);
            #pragma unroll
            for (int cq = 0; cq < 4; ++cq) {
                float4 wv = wr[cq];   // uniform addr -> broadcast b128
                acc[cq*4 + 0] += fv * wv.x;
                acc[cq*4 + 1] += fv * wv.y;
                acc[cq*4 + 2] += fv * wv.z;
                acc[cq*4 + 3] += fv * wv.w;
            }
        }
    }

    const float iv  = invn[row];
    const float mf  = (float)mask[row];
    const float nmf = 1.0f - mf;
    const float P100 = 2.6561398887587544e-5f;  // 0.9^100

    float p[16];
    #pragma unroll
    for (int c = 0; c < 16; ++c) {
        float lf  = (float)lab[(size_t)row * C_DIM + c];
        float upd = P100 * (lf * mf) + acc[c] * iv;   // 0.9^100 * p0 + D^-1 F W
        p[c] = upd * mf + lf * nmf;                   // literal mask arithmetic (NaN-faithful)
    }

    // numpy-compatible argmax: NaN treated as greatest, first occurrence wins
    float best = p[0];
    int idx = 0;
    #pragma unroll
    for (int c = 1; c < 16; ++c) {
        bool take = (p[c] > best) || ((p[c] != p[c]) && !(best != best));
        if (take) { best = p[c]; idx = c; }
    }
    out[row] = (float)idx;
}

extern "C" void kernel_launch(void* const* d_in, const int* in_sizes, int n_in,
                              void* d_out, int out_size, void* d_ws, size_t ws_size,
                              hipStream_t stream) {
    const float* F   = (const float*)d_in[0];
    const int* lab   = (const int*)d_in[1];
    const int* mask  = (const int*)d_in[2];
    float* ws   = (float*)d_ws;
    float* pH   = ws + WS_PH;
    float* pA   = ws + WS_PA;
    float* pR   = ws + WS_PR;
    float* invn = ws + WS_INVN;
    float* W    = ws + WS_W;
    float* Hf   = ws + WS_HF;
    float* Af   = ws + WS_AF;
    float* Rf   = ws + WS_RF;
    float* out  = (float*)d_out;

    lp_k1 <<<NBLK1, 256, 0, stream>>>(F, lab, mask, pH, pA, pR, invn);
    lp_k1b<<<24,    256, 0, stream>>>(pH, pA, pR, Hf, Af, Rf);
    lp_k2 <<<C_DIM,  64, 0, stream>>>(Hf, Af, Rf, W);
    lp_k3 <<<32,    256, 0, stream>>>(F, lab, mask, invn, W, out);
}

// Round 3
// 75.856 us; speedup vs baseline: 4.8487x; 1.9199x over previous
//
#include <hip/hip_runtime.h>
#include <math.h>

#define B_ROWS 8192
#define D_DIM 64
#define C_DIM 16
#define NBLK1 64
#define ROWS_PER_BLK 128   // 8192 / NBLK1
#define CHUNK 8

// ws layout (floats):
//   pH    : NBLK1 * 4096   = 262144
//   pA    : NBLK1 * 1024   =  65536
//   pR    : NBLK1 * 1024   =  65536
//   invn  : 8192
//   W     : 1024
//   Hfull : 4096
//   Afull : 1024
//   Rfull : 1024
#define WS_PH    0
#define WS_PA    262144
#define WS_PR    327680
#define WS_INVN  393216
#define WS_W     401408
#define WS_HF    402432
#define WS_AF    406528
#define WS_RF    407552

__global__ __launch_bounds__(256) void lp_k1(const float* __restrict__ F,
        const int* __restrict__ lab, const int* __restrict__ mask,
        float* __restrict__ pH, float* __restrict__ pA, float* __restrict__ pR,
        float* __restrict__ invn)
{
    __shared__ float cJ[ROWS_PER_BLK];      // mask_j * (1/||f_j||)
    __shared__ float fbuf[CHUNK][D_DIM];
    __shared__ float labf[CHUNK][C_DIM];
    __shared__ float mflag[CHUNK];
    const int t = threadIdx.x;
    const int row0 = blockIdx.x * ROWS_PER_BLK;

    // phase 1: row norms (threads 0..127, one row each)
    if (t < ROWS_PER_BLK) {
        const float4* fr = (const float4*)(F + (size_t)(row0 + t) * D_DIM);
        float ss = 0.0f;
        #pragma unroll
        for (int q = 0; q < 16; ++q) {
            float4 v = fr[q];
            ss += v.x*v.x + v.y*v.y + v.z*v.z + v.w*v.w;
        }
        float iv = 1.0f / sqrtf(ss);
        invn[row0 + t] = iv;
        cJ[t] = mask[row0 + t] ? iv : 0.0f;
    }
    __syncthreads();

    // phase 2: accumulate partial H (64x64), A (64x16), r0 (64x16)
    float h[16];
    float aacc[4], racc[4];
    #pragma unroll
    for (int k = 0; k < 16; ++k) h[k] = 0.0f;
    #pragma unroll
    for (int j = 0; j < 4; ++j) { aacc[j] = 0.0f; racc[j] = 0.0f; }

    const int d1  = t >> 2;          // H row owned by this thread
    const int d2b = (t & 3) << 4;    // H col block base (16 cols)

    for (int ch = 0; ch < ROWS_PER_BLK / CHUNK; ++ch) {
        for (int e = t; e < CHUNK * D_DIM; e += 256) {
            int r = e >> 6, d = e & 63;
            fbuf[r][d] = F[(size_t)(row0 + ch*CHUNK + r) * D_DIM + d];
        }
        if (t < CHUNK * C_DIM) {
            int r = t >> 4, c = t & 15;
            labf[r][c] = (float)lab[(size_t)(row0 + ch*CHUNK + r) * C_DIM + c];
        }
        if (t < CHUNK) mflag[t] = mask[row0 + ch*CHUNK + t] ? 1.0f : 0.0f;
        __syncthreads();

        #pragma unroll
        for (int r = 0; r < CHUNK; ++r) {
            float coef = cJ[ch*CHUNK + r];
            float fd1 = fbuf[r][d1] * coef;
            #pragma unroll
            for (int k = 0; k < 16; ++k)
                h[k] += fd1 * fbuf[r][d2b + k];
            float mf  = mflag[r];
            float nmf = 1.0f - mf;
            #pragma unroll
            for (int j = 0; j < 4; ++j) {
                int e = t*4 + j;
                int dd = e >> 4, cc = e & 15;
                float fl = fbuf[r][dd] * labf[r][cc];
                aacc[j] += nmf * fl;
                racc[j] += mf  * fl;
            }
        }
        __syncthreads();
    }

    #pragma unroll
    for (int k = 0; k < 16; ++k)
        pH[(size_t)blockIdx.x * 4096 + t*16 + k] = h[k];
    #pragma unroll
    for (int j = 0; j < 4; ++j) {
        pA[(size_t)blockIdx.x * 1024 + t*4 + j] = aacc[j];
        pR[(size_t)blockIdx.x * 1024 + t*4 + j] = racc[j];
    }
}

// reduce the 64 per-block partials -> Hfull (4096), Afull (1024), Rfull (1024)
__global__ __launch_bounds__(256) void lp_k1b(const float* __restrict__ pH,
        const float* __restrict__ pA, const float* __restrict__ pR,
        float* __restrict__ Hf, float* __restrict__ Af, float* __restrict__ Rf)
{
    const int e = blockIdx.x * 256 + threadIdx.x;   // 0..6143
    if (e < 4096) {
        float s = 0.0f;
        for (int b = 0; b < NBLK1; ++b) s += pH[(size_t)b * 4096 + e];
        Hf[e] = s;
    } else if (e < 5120) {
        const int i = e - 4096;
        float s = 0.0f;
        for (int b = 0; b < NBLK1; ++b) s += pA[(size_t)b * 1024 + i];
        Af[i] = s;
    } else {
        const int i = e - 5120;
        float s = 0.0f;
        for (int b = 0; b < NBLK1; ++b) s += pR[(size_t)b * 1024 + i];
        Rf[i] = s;
    }
}

// 16 independent column evolutions: block c, one wave, lane = d.
// H row in 64 VGPRs; per step only a 64-float LDS broadcast of g.
__global__ __launch_bounds__(64) void lp_k2(const float* __restrict__ Hf,
        const float* __restrict__ Af, const float* __restrict__ Rf,
        float* __restrict__ Wout)
{
    __shared__ __align__(16) float gs[64];
    const int d = threadIdx.x;
    const int c = blockIdx.x;

    float4 hq[16];
    const float4* Hrow = (const float4*)(Hf + d * 64);
    #pragma unroll
    for (int q = 0; q < 16; ++q) hq[q] = Hrow[q];

    float a = Af[d * 16 + c];
    float r = Rf[d * 16 + c];
    float w = 0.0f;

    for (int it = 0; it < 100; ++it) {
        float g = r + (it > 0 ? a : 0.0f);   // G_t = r_t + A (t>=1)
        w = 0.9f * w + 0.1f * g;
        gs[d] = g;
        __syncthreads();
        float acc0 = 0.0f, acc1 = 0.0f, acc2 = 0.0f, acc3 = 0.0f;
        #pragma unroll
        for (int q = 0; q < 16; ++q) {
            const float4 gv = *((const float4*)(gs + q * 4));  // uniform addr -> broadcast
            acc0 += hq[q].x * gv.x;
            acc1 += hq[q].y * gv.y;
            acc2 += hq[q].z * gv.z;
            acc3 += hq[q].w * gv.w;
        }
        r = 0.9f * r + 0.1f * ((acc0 + acc1) + (acc2 + acc3));
        __syncthreads();
    }
    Wout[d * 16 + c] = w;
}

// one row per thread; q-loop NOT unrolled so only one 64-float Ws slice is
// live per scheduling region (prevents the R1 load-clustering -> 256 VGPR
// -> 16 MB scratch-spill disaster)
__global__ __launch_bounds__(64) void lp_k3(const float* __restrict__ F,
        const int* __restrict__ lab, const int* __restrict__ mask,
        const float* __restrict__ invn, const float* __restrict__ Win,
        float* __restrict__ out)
{
    __shared__ __align__(16) float Ws[1024];   // [64][16] row-major
    const int t = threadIdx.x;                 // 0..63
    #pragma unroll
    for (int j = 0; j < 4; ++j)
        ((float4*)Ws)[j * 64 + t] = ((const float4*)Win)[j * 64 + t];
    __syncthreads();

    const int row = blockIdx.x * 64 + t;
    const float4* fr = (const float4*)(F + (size_t)row * D_DIM);

    float acc[16];
    #pragma unroll
    for (int c = 0; c < 16; ++c) acc[c] = 0.0f;

    #pragma unroll 1
    for (int q = 0; q < 16; ++q) {
        float4 v = fr[q];
        #pragma unroll
        for (int dd = 0; dd < 4; ++dd) {
            const float fv = (dd == 0) ? v.x : (dd == 1) ? v.y : (dd == 2) ? v.z : v.w;
            const float4* wr = (const float4*)(Ws + (q * 4 + dd) * 16);
            #pragma unroll
            for (int cq = 0; cq < 4; ++cq) {
                float4 wv = wr[cq];   // uniform addr -> broadcast b128
                acc[cq*4 + 0] += fv * wv.x;
                acc[cq*4 + 1] += fv * wv.y;
                acc[cq*4 + 2] += fv * wv.z;
                acc[cq*4 + 3] += fv * wv.w;
            }
        }
    }

    const float iv  = invn[row];
    const float mf  = (float)mask[row];
    const float nmf = 1.0f - mf;
    const float P100 = 2.6561398887587544e-5f;  // 0.9^100

    const int4* lr = (const int4*)(lab + (size_t)row * C_DIM);
    int li[16];
    #pragma unroll
    for (int g4 = 0; g4 < 4; ++g4) {
        int4 lv = lr[g4];
        li[g4*4 + 0] = lv.x; li[g4*4 + 1] = lv.y;
        li[g4*4 + 2] = lv.z; li[g4*4 + 3] = lv.w;
    }

    float p[16];
    #pragma unroll
    for (int c = 0; c < 16; ++c) {
        float lf  = (float)li[c];
        float upd = P100 * (lf * mf) + acc[c] * iv;   // 0.9^100 * p0 + D^-1 F W
        p[c] = upd * mf + lf * nmf;                   // literal mask arithmetic (NaN-faithful)
    }

    // numpy-compatible argmax: NaN treated as greatest, first occurrence wins
    float best = p[0];
    int idx = 0;
    #pragma unroll
    for (int c = 1; c < 16; ++c) {
        bool take = (p[c] > best) || ((p[c] != p[c]) && !(best != best));
        if (take) { best = p[c]; idx = c; }
    }
    out[row] = (float)idx;
}

extern "C" void kernel_launch(void* const* d_in, const int* in_sizes, int n_in,
                              void* d_out, int out_size, void* d_ws, size_t ws_size,
                              hipStream_t stream) {
    const float* F   = (const float*)d_in[0];
    const int* lab   = (const int*)d_in[1];
    const int* mask  = (const int*)d_in[2];
    float* ws   = (float*)d_ws;
    float* pH   = ws + WS_PH;
    float* pA   = ws + WS_PA;
    float* pR   = ws + WS_PR;
    float* invn = ws + WS_INVN;
    float* W    = ws + WS_W;
    float* Hf   = ws + WS_HF;
    float* Af   = ws + WS_AF;
    float* Rf   = ws + WS_RF;
    float* out  = (float*)d_out;

    lp_k1 <<<NBLK1, 256, 0, stream>>>(F, lab, mask, pH, pA, pR, invn);
    lp_k1b<<<24,    256, 0, stream>>>(pH, pA, pR, Hf, Af, Rf);
    lp_k2 <<<C_DIM,  64, 0, stream>>>(Hf, Af, Rf, W);
    lp_k3 <<<128,    64, 0, stream>>>(F, lab, mask, invn, W, out);
}